// Round 3
// baseline (274.763 us; speedup 1.0000x reference)
//
#include <hip/hip_runtime.h>
#include <hip/hip_bf16.h>

// out[b,e] = m[c,e] + sum_d z[b,d] * L[c,e,d],  c = components[b]
// fp32 in/out; bf16 MFMA inside. Round-3: pre-convert z to bf16 (ws), shrink
// LDS stage to 18KB (Z bf16 10K + L fp32 8K), double-buffer = 36KB -> 4
// blocks/CU residency to overlap barrier drains; XOR bank swizzles; skip
// staging Z row-groups beyond the component's count.

#define DDIM  2048
#define BSAMP 1024
#define KCOMP 10
#define MPAD  160
#define NT    64
#define BK    32
#define ZREG  10240                 // 160 rows x 32 bf16 (64 B/row)
#define STAGE 18432                 // + 64 rows x 32 f32 (128 B/row) = 8192

typedef __attribute__((ext_vector_type(8))) short bf16x8;
typedef __attribute__((ext_vector_type(4))) float f32x4;

__device__ __forceinline__ void async16(void* lds, const void* g) {
    __builtin_amdgcn_global_load_lds(
        (const __attribute__((address_space(1))) void*)g,
        (__attribute__((address_space(3))) void*)lds, 16, 0, 0);
}
__device__ __forceinline__ short bfs(float x) {
    __hip_bfloat16 h = __float2bfloat16(x);
    return *reinterpret_cast<short*>(&h);
}
__device__ __forceinline__ bf16x8 packB(const char* rowb, int o0, int o1) {
    f32x4 x = *(const f32x4*)(rowb + o0);
    f32x4 y = *(const f32x4*)(rowb + o1);
    bf16x8 r;
#pragma unroll
    for (int i = 0; i < 4; ++i) { r[i] = bfs(x[i]); r[4 + i] = bfs(y[i]); }
    return r;
}

__global__ void build_map(const int* __restrict__ comp,
                          int* __restrict__ rowmap,
                          int* __restrict__ counts) {
    __shared__ int sc[KCOMP];
    const int t = threadIdx.x;
    if (t < KCOMP) sc[t] = 0;
    __syncthreads();
    const int c = comp[t];
    const int r = atomicAdd(&sc[c], 1);
    if (r < MPAD) rowmap[c * MPAD + r] = t;
    __syncthreads();
    if (t < KCOMP) counts[t] = sc[t];
}

// fp32 -> bf16 convert of z (2M elems). grid 1024 x 256, 8 elems/thread.
__global__ void zconv(const float* __restrict__ z, short* __restrict__ zb) {
    const int i = (blockIdx.x * 256 + threadIdx.x) * 8;
    f32x4 a = *(const f32x4*)(z + i);
    f32x4 b = *(const f32x4*)(z + i + 4);
    bf16x8 o;
#pragma unroll
    for (int j = 0; j < 4; ++j) { o[j] = bfs(a[j]); o[4 + j] = bfs(b[j]); }
    *(bf16x8*)(zb + i) = o;
}

__device__ __forceinline__ int swz(int r) { return (r & 3) ^ ((r >> 2) & 3); }

// grid (32, 10), 256 thr (4 waves). Block tile 160x64, wave 80x32.
__global__ __launch_bounds__(256, 4)
void gmm_bf16z(const short* __restrict__ zb,
               const float* __restrict__ mvec,
               const float* __restrict__ Lmat,
               const int* __restrict__ rowmap,
               const int* __restrict__ counts,
               float* __restrict__ out) {
    __shared__ __attribute__((aligned(16))) char smem[2 * STAGE];
    const int t = threadIdx.x, lane = t & 63;
    const int w = t >> 6, mh = w >> 1, nh = w & 1;
    const int k = blockIdx.y, n0 = blockIdx.x * NT;
    const float* Lk = Lmat + (size_t)k * DDIM * DDIM;
    const int cnt = counts[k];

    // ---- staging precompute (slot-linear LDS, XOR-swizzled column data) ----
    // Z region: slot s -> row s>>2, cslot s&3, data colgrp = cslot ^ swz(row)
    // groups: g0 slots 0..255 (rows 0..63), g1 256..511 (64..127),
    //         g2a 512..639 t<128 (128..159)
    // L region: slot m -> row m>>3, cslot m&7, data colgrp = cslot ^ (row&7)
    // groups: g2b t>=128 slots 0..127 (rows 0..15), g3 128..383 (16..47),
    //         g4 t<128 384..511 (48..63)
    const int zq = t >> 2, zcs = t & 3;
    const int zr1 = 64 + zq, zr2 = 128 + zq;
    const int rmB = k * MPAD;
    const int rm0 = rowmap[rmB + zq] & (BSAMP - 1);
    const int rm1 = rowmap[rmB + zr1] & (BSAMP - 1);
    const int rm2 = rowmap[rmB + ((zr2 < MPAD) ? zr2 : 0)] & (BSAMP - 1);
    const short* zp0 = zb + (size_t)rm0 * DDIM + (zcs ^ swz(zq)) * 8;
    const short* zp1 = zb + (size_t)rm1 * DDIM + (zcs ^ swz(zr1)) * 8;
    const short* zp2 = zb + (size_t)rm2 * DDIM + (zcs ^ swz(zr2)) * 8;
    const int lcs = t & 7;
    const int lr2 = (t >= 128) ? ((t - 128) >> 3) : 0;
    const int lr3 = 16 + (t >> 3);
    const int lr4 = 48 + (t >> 3);                      // t<128 only
    const float* lp2 = Lk + (size_t)(n0 + lr2) * DDIM + (lcs ^ (lr2 & 7)) * 4;
    const float* lp3 = Lk + (size_t)(n0 + lr3) * DDIM + (lcs ^ (lr3 & 7)) * 4;
    const float* lp4 = Lk + (size_t)(n0 + (lr4 & 63)) * DDIM + (lcs ^ (lr4 & 7)) * 4;
    const int ub  = (t & ~63) << 4;                     // slot==t groups
    const int ubh = ((t - 128) & ~63) << 4;             // t>=128, slot==t-128
    const bool lowHalf = (t < 128);
    const bool st1 = (cnt > 64), st2 = (cnt > 128);

    auto stage = [&](int buf, int it) {
        char* lb = smem + buf * STAGE;
        const int d = it * BK;
        async16(lb + ub, zp0 + d);
        if (st1) async16(lb + 4096 + ub, zp1 + d);
        if (lowHalf) {
            if (st2) async16(lb + 8192 + ub, zp2 + d);
            async16(lb + ZREG + 6144 + ub, lp4 + d);    // L rows 48..63
        } else {
            async16(lb + ZREG + ubh, lp2 + d);          // L rows 0..15
        }
        async16(lb + ZREG + 2048 + ub, lp3 + d);        // L rows 16..47
    };

    f32x4 acc[5][2];
#pragma unroll
    for (int mt = 0; mt < 5; ++mt)
#pragma unroll
        for (int nt = 0; nt < 2; ++nt) acc[mt][nt] = (f32x4){0.f, 0.f, 0.f, 0.f};

    stage(0, 0);
    __syncthreads();

    const int fr = lane & 15, g = lane >> 4;
    const int szA   = (fr & 3) ^ ((fr >> 2) & 3);
    const int aoff  = ((g ^ szA) & 3) * 16;
    const int boff0 = (((g * 2)     ^ (fr & 7)) & 7) * 16;
    const int boff1 = (((g * 2 + 1) ^ (fr & 7)) & 7) * 16;
    const int rb0 = (nh * 32 + fr) * 128, rb1 = (nh * 32 + 16 + fr) * 128;
    const int raB = (mh * 80 + fr) * 64;

    for (int it = 0; it < DDIM / BK; ++it) {
        if (it + 1 < DDIM / BK) stage((it + 1) & 1, it + 1);
        const char* lb = smem + (it & 1) * STAGE;
        const char* Lb = lb + ZREG;
        bf16x8 b0 = packB(Lb + rb0, boff0, boff1);
        bf16x8 b1 = packB(Lb + rb1, boff0, boff1);
#pragma unroll
        for (int mt = 0; mt < 5; ++mt) {
            bf16x8 a = *(const bf16x8*)(lb + raB + mt * 16 * 64 + aoff);
            acc[mt][0] = __builtin_amdgcn_mfma_f32_16x16x32_bf16(a, b0, acc[mt][0], 0, 0, 0);
            acc[mt][1] = __builtin_amdgcn_mfma_f32_16x16x32_bf16(a, b1, acc[mt][1], 0, 0, 0);
        }
        __syncthreads();
    }

    // epilogue: C/D col=lane&15, row=(lane>>4)*4+reg
    const int rquad = (lane >> 4) * 4;
#pragma unroll
    for (int nt = 0; nt < 2; ++nt) {
        const int e = n0 + nh * 32 + nt * 16 + fr;
        const float mu = mvec[k * DDIM + e];
#pragma unroll
        for (int mt = 0; mt < 5; ++mt) {
            const int sb = mh * 80 + mt * 16 + rquad;
#pragma unroll
            for (int r = 0; r < 4; ++r) {
                const int slot = sb + r;
                if (slot < cnt) {
                    const int b = rowmap[rmB + slot];
                    out[(size_t)b * DDIM + e] = acc[mt][nt][r] + mu;
                }
            }
        }
    }
}

// ---------------- fallback (round-2 proven): fp32 staging, no ws zb --------
__device__ __forceinline__ bf16x8 frag8(const char* base, int o0, int o1) {
    f32x4 x = *(const f32x4*)(base + o0);
    f32x4 y = *(const f32x4*)(base + o1);
    bf16x8 r;
#pragma unroll
    for (int i = 0; i < 4; ++i) { r[i] = bfs(x[i]); r[4 + i] = bfs(y[i]); }
    return r;
}
__global__ __launch_bounds__(256, 2)
void gmm_f32z(const float* __restrict__ z, const float* __restrict__ mvec,
              const float* __restrict__ Lmat, const int* __restrict__ rowmap,
              const int* __restrict__ counts, float* __restrict__ out) {
    __shared__ __attribute__((aligned(16))) char smem[2 * 28672];
    const int t = threadIdx.x, lane = t & 63, w = t >> 6;
    const int mh = w >> 1, nh = w & 1;
    const int k = blockIdx.y, n0 = blockIdx.x * NT;
    const float* Lk = Lmat + (size_t)k * DDIM * DDIM;
    const int rq = t >> 3;
    const int scol = ((t & 7) ^ (rq & 7)) * 4;
    int rm[5];
#pragma unroll
    for (int j = 0; j < 5; ++j)
        rm[j] = rowmap[k * MPAD + j * 32 + rq] & (BSAMP - 1);
    const unsigned ub = (unsigned)(t & ~63) * 16;
    auto stage = [&](int buf, int it) {
        char* lb = smem + buf * 28672;
        const int d0 = it * 32 + scol;
#pragma unroll
        for (int j = 0; j < 5; ++j)
            async16(lb + j * 4096 + ub, z + (size_t)rm[j] * DDIM + d0);
        async16(lb + 20480 + ub,        Lk + (size_t)(n0 + rq) * DDIM + d0);
        async16(lb + 20480 + 4096 + ub, Lk + (size_t)(n0 + 32 + rq) * DDIM + d0);
    };
    f32x4 acc[5][2];
#pragma unroll
    for (int mt = 0; mt < 5; ++mt)
#pragma unroll
        for (int nt = 0; nt < 2; ++nt) acc[mt][nt] = (f32x4){0.f, 0.f, 0.f, 0.f};
    stage(0, 0);
    __syncthreads();
    const int fr = lane & 15, g0 = (lane >> 4) * 2;
    for (int it = 0; it < DDIM / 32; ++it) {
        if (it + 1 < DDIM / 32) stage((it + 1) & 1, it + 1);
        const char* lb = smem + (it & 1) * 28672;
        const int rb0 = nh * 32 + fr, rb1 = rb0 + 16;
        bf16x8 b0 = frag8(lb + 20480, rb0 * 128 + ((g0 ^ rb0) & 7) * 16,
                          rb0 * 128 + (((g0 + 1) ^ rb0) & 7) * 16);
        bf16x8 b1 = frag8(lb + 20480, rb1 * 128 + ((g0 ^ rb1) & 7) * 16,
                          rb1 * 128 + (((g0 + 1) ^ rb1) & 7) * 16);
#pragma unroll
        for (int mt = 0; mt < 5; ++mt) {
            const int ra = mh * 80 + mt * 16 + fr;
            bf16x8 a = frag8(lb, ra * 128 + ((g0 ^ ra) & 7) * 16,
                             ra * 128 + (((g0 + 1) ^ ra) & 7) * 16);
            acc[mt][0] = __builtin_amdgcn_mfma_f32_16x16x32_bf16(a, b0, acc[mt][0], 0, 0, 0);
            acc[mt][1] = __builtin_amdgcn_mfma_f32_16x16x32_bf16(a, b1, acc[mt][1], 0, 0, 0);
        }
        __syncthreads();
    }
    const int cnt = counts[k], rquad = (lane >> 4) * 4;
#pragma unroll
    for (int nt = 0; nt < 2; ++nt) {
        const int e = n0 + nh * 32 + nt * 16 + fr;
        const float mu = mvec[k * DDIM + e];
#pragma unroll
        for (int mt = 0; mt < 5; ++mt) {
            const int sb = mh * 80 + mt * 16 + rquad;
#pragma unroll
            for (int r = 0; r < 4; ++r) {
                const int slot = sb + r;
                if (slot < cnt)
                    out[(size_t)rowmap[k * MPAD + slot] * DDIM + e] = acc[mt][nt][r] + mu;
            }
        }
    }
}

extern "C" void kernel_launch(void* const* d_in, const int* in_sizes, int n_in,
                              void* d_out, int out_size, void* d_ws, size_t ws_size,
                              hipStream_t stream) {
    const float* z    = (const float*)d_in[0];
    const float* mvec = (const float*)d_in[1];
    const float* Lmat = (const float*)d_in[2];
    const int* comp   = (const int*)d_in[3];
    float* out        = (float*)d_out;

    int* rowmap = (int*)d_ws;                     // 6400 B
    int* counts = rowmap + KCOMP * MPAD;
    build_map<<<1, BSAMP, 0, stream>>>(comp, rowmap, counts);

    const size_t need = 8192 + (size_t)BSAMP * DDIM * 2;   // zb at ws+8KB
    if (ws_size >= need) {
        short* zbuf = (short*)((char*)d_ws + 8192);
        zconv<<<BSAMP * DDIM / (256 * 8), 256, 0, stream>>>(z, zbuf);
        gmm_bf16z<<<dim3(DDIM / NT, KCOMP), 256, 0, stream>>>(
            zbuf, mvec, Lmat, rowmap, counts, out);
    } else {
        gmm_f32z<<<dim3(DDIM / NT, KCOMP), 256, 0, stream>>>(
            z, mvec, Lmat, rowmap, counts, out);
    }
}